// Round 1
// baseline (293.285 us; speedup 1.0000x reference)
//
#include <hip/hip_runtime.h>

// Problem constants (from reference setup_inputs)
#define BB  8
#define PP  16384
#define KK  16384
#define NN  16
#define CIN 64
#define REL 3
#define CC  67   // CIN + REL
#define OUTC 64

// One wave (64 lanes) per output row (b,k). lane = channel.
// Wave w handles k = w, looping b = 0..7 (batch-strided so concurrent waves
// share one 4MB feats slab -> L2 locality for the random gather).
__global__ __launch_bounds__(256, 4) void graphconv_kernel(
    const float* __restrict__ feats,        // [B, P, CIN]
    const int*   __restrict__ n_idxs,       // [B, K, N]
    const float* __restrict__ neighbor_rel, // [B, K, N, REL]
    const int*   __restrict__ neighbor_valid,// [B, K, N]
    const float* __restrict__ Wm,           // [OUTC, CC]
    const float* __restrict__ bvec,         // [OUTC]
    float*       __restrict__ out)          // [B, K, OUTC]
{
    const int lane = threadIdx.x & 63;
    // force wave id scalar so all row-level addresses are provably uniform
    const int wave_in_block = __builtin_amdgcn_readfirstlane((int)(threadIdx.x >> 6));
    const int k = blockIdx.x * 4 + wave_in_block;   // 0..16383

    // Per-lane persistent: W row for output channel `lane`, and its bias.
    float wreg[CC];
#pragma unroll
    for (int c = 0; c < CC; ++c) wreg[c] = Wm[lane * CC + c];
    const float bias = bvec[lane];

    for (int b = 0; b < BB; ++b) {
        const size_t row  = (size_t)b * KK + (size_t)k;
        const int*   idxp = n_idxs        + row * NN;
        const int*   vp   = neighbor_valid + row * NN;
        const float* relp = neighbor_rel  + row * (NN * REL);
        const float* fb   = feats + (size_t)b * ((size_t)PP * CIN);

        float sum = 0.0f;                 // per-lane: channel `lane` of masked sum
        float r0 = 0.0f, r1 = 0.0f, r2 = 0.0f;  // uniform rel sums (redundant per lane)
        int count = 0;                    // uniform valid count
#pragma unroll
        for (int n = 0; n < NN; ++n) {
            const int v = vp[n];          // uniform scalar load
            if (v) {                      // uniform branch: skips gather for invalid
                const int id = idxp[n];   // uniform scalar load
                sum += fb[(size_t)id * CIN + lane];   // coalesced 256B gather
                r0  += relp[n * 3 + 0];   // uniform scalar loads
                r1  += relp[n * 3 + 1];
                r2  += relp[n * 3 + 2];
                count += 1;
            }
        }

        const float inv = (count > 0) ? (1.0f / (float)count) : 0.0f;

        // Transpose-free dot: lane o computes sum_c scaled[c] * W[o][c].
        // Broadcast each channel's sum via v_readlane (VALU, spread over 4 SIMDs).
        float dot = 0.0f;
#pragma unroll
        for (int c = 0; c < CIN; ++c) {
            const float sc = __int_as_float(
                __builtin_amdgcn_readlane(__float_as_int(sum), c));
            dot = fmaf(sc, wreg[c], dot);
        }
        dot = fmaf(r0, wreg[CIN + 0], dot);
        dot = fmaf(r1, wreg[CIN + 1], dot);
        dot = fmaf(r2, wreg[CIN + 2], dot);

        const float o = fmaf(dot, inv, bias);   // scaling folded past the dot
        out[row * OUTC + lane] = fmaxf(o, 0.0f); // coalesced 256B store
    }
}

extern "C" void kernel_launch(void* const* d_in, const int* in_sizes, int n_in,
                              void* d_out, int out_size, void* d_ws, size_t ws_size,
                              hipStream_t stream) {
    // setup_inputs order: keys(0), points(1), feats(2), n_idxs(3),
    // neighbor_rel(4), neighbor_valid(5), W(6), b(7). keys/points unused.
    const float* feats = (const float*)d_in[2];
    const int*   nidx  = (const int*)  d_in[3];
    const float* nrel  = (const float*)d_in[4];
    const int*   nval  = (const int*)  d_in[5];
    const float* Wm    = (const float*)d_in[6];
    const float* bv    = (const float*)d_in[7];
    float* out = (float*)d_out;

    // 4096 blocks x 4 waves = 16384 waves = K. Each wave: 8 rows (one per batch).
    graphconv_kernel<<<dim3(4096), dim3(256), 0, stream>>>(
        feats, nidx, nrel, nval, Wm, bv, out);
}

// Round 2
// 187.199 us; speedup vs baseline: 1.5667x; 1.5667x over previous
//
#include <hip/hip_runtime.h>

// Problem constants (from reference setup_inputs)
#define BB  8
#define PP  16384
#define KK  16384
#define NN  16
#define CIN 64
#define REL 3
#define CC  67          // CIN + REL
#define OUTC 64
#define WTOT (OUTC * CC) // 4288 floats = 17152 B LDS

// One wave per k, looping b=0..7 (concurrent waves share each 4MB feats slab
// -> L2 locality for the random gather). lane = channel (in) / out-channel.
//
// Round-2 fixes vs round 1 (200us):
//  * BRANCHLESS: all metadata loaded unconditionally as uniform scalar loads
//    (compiler merges + hoists; one lgkmcnt wait per row instead of 16
//    serialized s_cbranch/s_load/gather chains). Invalid neighbors are
//    mask-multiplied, not skipped.
//  * W comes from LDS, not 268B-strided scattered global loads. Staged
//    coalesced once per block; per-wave copy to VGPRs via 67 conflict-free
//    ds_read_b32 (stride 67 dwords is odd -> 2 lanes/bank = free).
__global__ __launch_bounds__(256, 4) void graphconv_kernel(
    const float* __restrict__ feats,         // [B, P, CIN]
    const int*   __restrict__ n_idxs,        // [B, K, N]
    const float* __restrict__ neighbor_rel,  // [B, K, N, REL]
    const int*   __restrict__ neighbor_valid,// [B, K, N]
    const float* __restrict__ Wm,            // [OUTC, CC]
    const float* __restrict__ bvec,          // [OUTC]
    float*       __restrict__ out)           // [B, K, OUTC]
{
    __shared__ float lds_w[WTOT];
    for (int i = threadIdx.x; i < WTOT; i += 256) lds_w[i] = Wm[i];
    __syncthreads();

    const int lane = threadIdx.x & 63;
    const int wave = __builtin_amdgcn_readfirstlane((int)(threadIdx.x >> 6));
    const int k = blockIdx.x * 4 + wave;     // 0..16383

    // Per-lane W row for output channel `lane`, held in VGPRs (reused 8 rows).
    float wreg[CC];
#pragma unroll
    for (int c = 0; c < CC; ++c) wreg[c] = lds_w[lane * CC + c];
    const float bias = bvec[lane];

    for (int b = 0; b < BB; ++b) {
        const size_t row  = (size_t)b * KK + (size_t)k;
        const int*   idxp = n_idxs         + row * NN;   // uniform
        const int*   vp   = neighbor_valid + row * NN;   // uniform
        const float* relp = neighbor_rel   + row * (NN * REL); // uniform
        const float* fb   = feats + (size_t)b * ((size_t)PP * CIN);

        float sum = 0.0f;                    // per-lane channel sum
        float r0 = 0.0f, r1 = 0.0f, r2 = 0.0f;
        int count = 0;
#pragma unroll
        for (int n = 0; n < NN; ++n) {
            const int   v  = vp[n];          // uniform s_load (no branch!)
            const int   id = idxp[n];        // uniform s_load
            const float m  = (float)v;
            // uniform base + lane*4 -> saddr-form coalesced 256B gather
            const float g  = fb[(size_t)id * CIN + lane];
            sum = fmaf(m, g, sum);
            r0  = fmaf(m, relp[n * 3 + 0], r0);
            r1  = fmaf(m, relp[n * 3 + 1], r1);
            r2  = fmaf(m, relp[n * 3 + 2], r2);
            count += v;
        }

        const float inv = (count > 0) ? (1.0f / (float)count) : 0.0f;

        // lane o: dot = sum_c scaled[c] * W[o][c], broadcasting channel sums
        // via v_readlane. 4 accumulators break the serial FMA chain.
        float d0 = 0.0f, d1 = 0.0f, d2 = 0.0f, d3 = 0.0f;
#pragma unroll
        for (int c = 0; c < CIN; c += 4) {
            const float s0 = __int_as_float(
                __builtin_amdgcn_readlane(__float_as_int(sum), c + 0));
            const float s1 = __int_as_float(
                __builtin_amdgcn_readlane(__float_as_int(sum), c + 1));
            const float s2 = __int_as_float(
                __builtin_amdgcn_readlane(__float_as_int(sum), c + 2));
            const float s3 = __int_as_float(
                __builtin_amdgcn_readlane(__float_as_int(sum), c + 3));
            d0 = fmaf(s0, wreg[c + 0], d0);
            d1 = fmaf(s1, wreg[c + 1], d1);
            d2 = fmaf(s2, wreg[c + 2], d2);
            d3 = fmaf(s3, wreg[c + 3], d3);
        }
        d0 = fmaf(r0, wreg[CIN + 0], d0);
        d1 = fmaf(r1, wreg[CIN + 1], d1);
        d2 = fmaf(r2, wreg[CIN + 2], d2);
        const float dot = (d0 + d1) + (d2 + d3);

        const float o = fmaf(dot, inv, bias);    // inv folded past the dot
        out[row * OUTC + lane] = fmaxf(o, 0.0f); // coalesced 256B store
    }
}

extern "C" void kernel_launch(void* const* d_in, const int* in_sizes, int n_in,
                              void* d_out, int out_size, void* d_ws, size_t ws_size,
                              hipStream_t stream) {
    // setup_inputs order: keys(0), points(1), feats(2), n_idxs(3),
    // neighbor_rel(4), neighbor_valid(5), W(6), b(7). keys/points unused.
    const float* feats = (const float*)d_in[2];
    const int*   nidx  = (const int*)  d_in[3];
    const float* nrel  = (const float*)d_in[4];
    const int*   nval  = (const int*)  d_in[5];
    const float* Wm    = (const float*)d_in[6];
    const float* bv    = (const float*)d_in[7];
    float* out = (float*)d_out;

    // 4096 blocks x 4 waves = 16384 waves = K; each wave does 8 rows (b loop).
    graphconv_kernel<<<dim3(4096), dim3(256), 0, stream>>>(
        feats, nidx, nrel, nval, Wm, bv, out);
}